// Round 17
// baseline (66.587 us; speedup 1.0000x reference)
//
#include <hip/hip_runtime.h>

#define N 8192
#define EPS 1e-5f
#define LOG2E 1.4426950408889634f
#define LN2d  0.6931471805599453

#define TR 64          // rows per tile
#define TC 256         // cols per tile
#define NBJ 32         // N/TC col-tiles
#define NBI 128        // N/TR row-tiles
#define RPW 16         // rows per wave (4 waves/block)
#define CAPW 512       // per-wave LDS edge buffer entries (flush at >256; max 256/row)
#define SEG_W 4096     // worst-case edges per wave segment (RPW*TC) -> never overflows
#define NTILES 2112    // active upper-tri tiles
#define NSEG (NTILES * 4)
#define NDENSE 4096    // dense pair-blocks
#define NFB 1024       // fallback blocks (tiny-ws path only)
#define TBLMAX 1024    // max degree-value range for the LDS table path

// ws layout (bytes):
//   accv [0,4096)   64 double slots, stride 8 doubles (1/cache line)
//   deg  [4096, +32768)          -- memset once with accv (36864 B total)
//   cnt  [36864, +NSEG*4)
//   edges[..., +NSEG*SEG_W*4)    total ~138 MB
static const size_t OFF_ACC = 0;
static const size_t OFF_DEG = 4096;
static const size_t OFF_CNT = OFF_DEG + (size_t)N * 4;
static const size_t OFF_EDG = OFF_CNT + (size_t)NSEG * 4;
static const size_t WS_NEED = OFF_EDG + (size_t)NSEG * SEG_W * 4;

__device__ __forceinline__ unsigned mbcnt64(unsigned long long m) {
    return __builtin_amdgcn_mbcnt_hi((unsigned)(m >> 32),
           __builtin_amdgcn_mbcnt_lo((unsigned)m, 0u));
}

// Pass 1 (round-12 body, the 4x-proven champion): stream the upper triangle
// once. Row sums via popc of ballots (graph values are exactly 0/1). Edge
// compaction: ballot-rank into a per-wave LDS buffer (count in a
// wave-uniform register), coalesced flush to a deterministic per-(tile,wave)
// global segment. Rounds 8/13/14/15 all failed to beat this body's ~31 us:
// it sits at this access pattern's practical BW/latency ceiling.
__global__ __launch_bounds__(256) void k_pass1(const float* __restrict__ g,
        float* __restrict__ deg, unsigned* __restrict__ cnt,
        unsigned* __restrict__ edges, const int segmode) {
    const int bj = (int)blockIdx.x & (NBJ - 1);
    const int bi = (int)blockIdx.x >> 5;
    if (bi > 4 * bj + 3) return;                 // tile fully below diagonal
    const int r0 = bi * TR, c0 = bj * TC;
    const int wave = threadIdx.x >> 6, lane = threadIdx.x & 63;
    const int aid = 2 * bj * (bj + 1) + bi;      // compact active-tile index

    __shared__ float    scol[TC];
    __shared__ unsigned buf[4][CAPW];
    scol[threadIdx.x] = 0.f;
    __syncthreads();

    const int c = c0 + lane * 4;
    const int rbase = r0 + wave * RPW;
    const float* __restrict__ gp = g + (size_t)rbase * N + c;
    unsigned* __restrict__ myseg = edges + ((size_t)aid * 4 + wave) * SEG_W;
    unsigned wc = 0, wflushed = 0;               // wave-uniform registers
    float ca0 = 0.f, ca1 = 0.f, ca2 = 0.f, ca3 = 0.f;

#define EMIT(BB, PRED, OFFv) \
    if (BB) { if (segmode && (PRED)) buf[wave][wc + mbcnt64(BB)] = etag | (OFFv); \
        const unsigned p_ = __popcll(BB); wc += p_; rsum += p_; }

#define FLUSHCHK \
    if (segmode && wc > (unsigned)(CAPW - 256)) { \
        for (unsigned t_ = lane; t_ < wc; t_ += 64) myseg[wflushed + t_] = buf[wave][t_]; \
        wflushed += wc; wc = 0; }

    if (r0 + TR <= c0) {
        // strictly-above-diagonal tile: every element is in the triangle
        #pragma unroll 4
        for (int k = 0; k < RPW; ++k) {
            const float4 v = *reinterpret_cast<const float4*>(gp + (size_t)k * N);
            FLUSHCHK
            ca0 += v.x; ca1 += v.y; ca2 += v.z; ca3 += v.w;
            const unsigned long long b0 = __ballot(v.x != 0.f);
            const unsigned long long b1 = __ballot(v.y != 0.f);
            const unsigned long long b2 = __ballot(v.z != 0.f);
            const unsigned long long b3 = __ballot(v.w != 0.f);
            if (b0 | b1 | b2 | b3) {
                const int gr = rbase + k;
                const unsigned etag = ((unsigned)gr << 16) | (unsigned)c;
                unsigned rsum = 0;
                EMIT(b0, v.x != 0.f, 0u)
                EMIT(b1, v.y != 0.f, 1u)
                EMIT(b2, v.z != 0.f, 2u)
                EMIT(b3, v.w != 0.f, 3u)
                if (lane == 0) atomicAdd(&deg[gr], (float)rsum);
            }
        }
    } else {
        // diagonal-crossing tile: per-element triangle masks
        for (int k = 0; k < RPW; ++k) {
            const int gr = rbase + k;
            const float4 v = *reinterpret_cast<const float4*>(gp + (size_t)k * N);
            FLUSHCHK
            const bool a0 = (v.x != 0.f) && (c + 0 >= gr);
            const bool a1 = (v.y != 0.f) && (c + 1 >= gr);
            const bool a2 = (v.z != 0.f) && (c + 2 >= gr);
            const bool a3 = (v.w != 0.f) && (c + 3 >= gr);
            ca0 += (c + 0 > gr) ? v.x : 0.f;
            ca1 += (c + 1 > gr) ? v.y : 0.f;
            ca2 += (c + 2 > gr) ? v.z : 0.f;
            ca3 += (c + 3 > gr) ? v.w : 0.f;
            const unsigned long long b0 = __ballot(a0);
            const unsigned long long b1 = __ballot(a1);
            const unsigned long long b2 = __ballot(a2);
            const unsigned long long b3 = __ballot(a3);
            if (b0 | b1 | b2 | b3) {
                const unsigned etag = ((unsigned)gr << 16) | (unsigned)c;
                unsigned rsum = 0;
                EMIT(b0, a0, 0u)
                EMIT(b1, a1, 1u)
                EMIT(b2, a2, 2u)
                EMIT(b3, a3, 3u)
                if (lane == 0) atomicAdd(&deg[gr], (float)rsum);
            }
        }
    }
#undef EMIT
#undef FLUSHCHK

    if (segmode) {
        for (unsigned t = lane; t < wc; t += 64) myseg[wflushed + t] = buf[wave][t];
        if (lane == 0) cnt[aid * 4 + wave] = wflushed + wc;
    }
    // column (strict-lower counterpart) sums: LDS-combine then one flush
    if (ca0 != 0.f) atomicAdd(&scol[lane * 4 + 0], ca0);
    if (ca1 != 0.f) atomicAdd(&scol[lane * 4 + 1], ca1);
    if (ca2 != 0.f) atomicAdd(&scol[lane * 4 + 2], ca2);
    if (ca3 != 0.f) atomicAdd(&scol[lane * 4 + 3], ca3);
    __syncthreads();
    const float sv = scol[threadIdx.x];
    if (sv != 0.f) atomicAdd(&deg[c0 + threadIdx.x], sv);
}

// Dense S0 (pair-balanced, per-row LDS lookup table over the block's degree
// range: R trans-evals instead of N+1, main loop = ld+cvt+ds_read+add, no
// trans) + edge corrections + fallback. Table entry (log2-domain):
//   t[i] = log2(1.00001 - rcp(1 + exp2(b2*(dmin+i) + base)));  sum * ln2
__global__ __launch_bounds__(256) void k_ll(const float* __restrict__ g,
        const float* __restrict__ deg, const float* __restrict__ params,
        const unsigned* __restrict__ cnt, const unsigned* __restrict__ edges,
        double* __restrict__ accv, const int segmode) {
    __shared__ float  tbl[2][TBLMAX];
    __shared__ double wsum[4];
    __shared__ float  rmn[4], rmx[4];
    const int tid = threadIdx.x;
    const int wv = tid >> 6, ln = tid & 63;
    const int b = blockIdx.x;
    const float alpha = params[0], beta = params[1], sigma = params[2];
    double dlocal = 0.0;

    if (b < NDENSE) {
        if (!segmode) return;                    // fallback covers everything
        const int r1 = b, r2 = N - 1 - b;        // pair rows: N+1 iters/block
        const float b2 = beta * LOG2E;
        const float base1 = fmaf(alpha, deg[r1], sigma) * LOG2E;
        const float base2 = fmaf(alpha, deg[r2], sigma) * LOG2E;

        // block-local degree range over exactly the indices we will read
        float mn = 3.0e38f, mx = -3.0e38f;
        for (int j = r1 + tid; j < N; j += 256) {
            const float d = deg[j];
            mn = fminf(mn, d); mx = fmaxf(mx, d);
        }
        #pragma unroll
        for (int off = 32; off; off >>= 1) {
            mn = fminf(mn, __shfl_xor(mn, off));
            mx = fmaxf(mx, __shfl_xor(mx, off));
        }
        if (ln == 0) { rmn[wv] = mn; rmx[wv] = mx; }
        __syncthreads();
        mn = fminf(fminf(rmn[0], rmn[1]), fminf(rmn[2], rmn[3]));
        mx = fmaxf(fmaxf(rmx[0], rmx[1]), fmaxf(rmx[2], rmx[3]));
        const int dmin = (int)mn;
        const int R = (int)mx - dmin + 1;

#define DEVAL(DV, BASE) \
        __builtin_amdgcn_logf(1.00001f - __builtin_amdgcn_rcpf(1.f + \
            __builtin_amdgcn_exp2f(fmaf(b2, (DV), (BASE)))))

        float l0 = 0.f, l1 = 0.f, l2 = 0.f, l3 = 0.f;
        if (R <= TBLMAX) {
            // build the two per-row tables (R trans-evals, not N+1)
            for (int i = tid; i < R; i += 256) {
                const float dv = (float)(dmin + i);
                tbl[0][i] = DEVAL(dv, base1);
                tbl[1][i] = DEVAL(dv, base2);
            }
            __syncthreads();
            int j = r1 + tid;
            for (; j + 768 < N; j += 1024) {
                l0 += tbl[0][(int)deg[j]       - dmin];
                l1 += tbl[0][(int)deg[j + 256] - dmin];
                l2 += tbl[0][(int)deg[j + 512] - dmin];
                l3 += tbl[0][(int)deg[j + 768] - dmin];
            }
            for (; j < N; j += 256) l0 += tbl[0][(int)deg[j] - dmin];
            j = r2 + tid;
            for (; j + 768 < N; j += 1024) {
                l0 += tbl[1][(int)deg[j]       - dmin];
                l1 += tbl[1][(int)deg[j + 256] - dmin];
                l2 += tbl[1][(int)deg[j + 512] - dmin];
                l3 += tbl[1][(int)deg[j + 768] - dmin];
            }
            for (; j < N; j += 256) l0 += tbl[1][(int)deg[j] - dmin];
        } else {
            // adversarial degree spread: direct trans path (round-12 proven)
            int j = r1 + tid;
            for (; j + 768 < N; j += 1024) {
                l0 += DEVAL(deg[j], base1);
                l1 += DEVAL(deg[j + 256], base1);
                l2 += DEVAL(deg[j + 512], base1);
                l3 += DEVAL(deg[j + 768], base1);
            }
            for (; j < N; j += 256) l0 += DEVAL(deg[j], base1);
            j = r2 + tid;
            for (; j + 768 < N; j += 1024) {
                l0 += DEVAL(deg[j], base2);
                l1 += DEVAL(deg[j + 256], base2);
                l2 += DEVAL(deg[j + 512], base2);
                l3 += DEVAL(deg[j + 768], base2);
            }
            for (; j < N; j += 256) l0 += DEVAL(deg[j], base2);
        }
#undef DEVAL
        dlocal = (double)((l0 + l1) + (l2 + l3)) * LN2d;
    } else if (b < NDENSE + NTILES) {
        if (!segmode) return;
        const int aid = b - NDENSE;
        float local = 0.f;
        for (int w = 0; w < 4; ++w) {
            const unsigned n = cnt[aid * 4 + w];
            const unsigned* __restrict__ seg = edges + ((size_t)aid * 4 + w) * SEG_W;
            for (unsigned t = tid; t < n; t += 256) {
                const unsigned e = seg[t];
                const float di = deg[e >> 16];
                const float dj = deg[e & 0xffffu];
                const float s = fmaf(alpha, di, fmaf(beta, dj, sigma));
                const float p = __fdividef(1.f, 1.f + __expf(s));
                local += __logf(p + EPS) - __logf(1.f - p + EPS);
            }
        }
        dlocal = (double)local;
    } else {
        if (segmode) return;                     // fallback only when ws tiny
        const int rb = b - NDENSE - NTILES;
        for (int q = 0; q < 8; ++q) {
            const int i = rb * 8 + q;
            const float base = fmaf(alpha, deg[i], sigma);
            float rl = 0.f;
            for (int j = i + tid; j < N; j += 256) {
                const float s = fmaf(beta, deg[j], base);
                const float p = __fdividef(1.f, 1.f + __expf(s));
                const float gv = g[(size_t)i * N + j];
                rl += (gv != 0.f) ? __logf(p + EPS) : __logf(1.f - p + EPS);
            }
            dlocal += (double)rl;
        }
    }

    #pragma unroll
    for (int off = 32; off; off >>= 1) dlocal += __shfl_xor(dlocal, off);
    if (ln == 0) wsum[wv] = dlocal;
    __syncthreads();
    if (tid == 0) {
        const double t = (wsum[0] + wsum[1]) + (wsum[2] + wsum[3]);
        if (t != 0.0) atomicAdd(&accv[(b & 63) * 8], t);   // 64 spread slots
    }
}

__global__ void k_final(const double* __restrict__ accv, float* __restrict__ out) {
    double v = accv[threadIdx.x * 8];
    #pragma unroll
    for (int off = 32; off; off >>= 1) v += __shfl_xor(v, off);
    if (threadIdx.x == 0) out[0] = (float)(-v);
}

extern "C" void kernel_launch(void* const* d_in, const int* in_sizes, int n_in,
                              void* d_out, int out_size, void* d_ws, size_t ws_size,
                              hipStream_t stream) {
    const float* params = (const float*)d_in[0];   // [alpha, beta, sigma]
    const float* graph  = (const float*)d_in[1];   // [N, N] fp32 0/1
    float* out = (float*)d_out;

    char* ws = (char*)d_ws;
    double*   accv  = (double*)(ws + OFF_ACC);
    float*    deg   = (float*)(ws + OFF_DEG);
    unsigned* cnt   = (unsigned*)(ws + OFF_CNT);
    unsigned* edges = (unsigned*)(ws + OFF_EDG);
    const int segmode = (ws_size >= WS_NEED) ? 1 : 0;

    hipMemsetAsync(ws, 0, OFF_DEG + (size_t)N * 4, stream);  // accv + deg
    k_pass1<<<NBI * NBJ, 256, 0, stream>>>(graph, deg, cnt, edges, segmode);
    const int llgrid = segmode ? (NDENSE + NTILES) : (NDENSE + NTILES + NFB);
    k_ll<<<llgrid, 256, 0, stream>>>(graph, deg, params, cnt, edges, accv, segmode);
    k_final<<<1, 64, 0, stream>>>(accv, out);
}